// Round 1
// baseline (6484.984 us; speedup 1.0000x reference)
//
#include <hip/hip_runtime.h>
#include <cstdint>
#include <cstddef>

// ---------------- problem constants ----------------
static constexpr int NB  = 32;      // batch
static constexpr int NT  = 22;      // caption length T
static constexpr int NP  = 196;     // pixels 14*14
static constexpr int NDE = 2048;    // encoder dim
static constexpr int NE  = 512;     // embed dim
static constexpr int NH  = 512;     // hidden
static constexpr int NA  = 512;     // attention dim
static constexpr int NV  = 30000;   // vocab
static constexpr int NTD = 20;      // Tdec = T-2
static constexpr int NKX = 3072;    // E + DE + H (concat x | h)

// ---------------- output offsets (floats) ----------------
static constexpr size_t OUT_PRED  = 0;
static constexpr size_t OUT_ALPHA = (size_t)NB*NTD*NV;            // 19,200,000
static constexpr size_t OUT_CAPS  = OUT_ALPHA + (size_t)NB*NTD*NP;// 19,325,440
static constexpr size_t OUT_LEN   = OUT_CAPS + (size_t)NB*NT;     // 19,326,144
static constexpr size_t OUT_SIDX  = OUT_LEN + NB;                 // 19,326,176

// ---------------- ws layout (floats; ints live in first 768) ----------------
// int region: [0,32) sidx | [32,64) declen | [64,768) caps_i (32*22=704)
static constexpr size_t WS_H     = 768;
static constexpr size_t WS_C     = WS_H    + (size_t)NB*NH;          // +16384
static constexpr size_t WS_MEAN  = WS_C    + (size_t)NB*NH;
static constexpr size_t WS_ALPHA = WS_MEAN + (size_t)NB*NDE;
static constexpr size_t WS_XCAT  = WS_ALPHA+ (size_t)NB*NP;
static constexpr size_t WS_PART  = WS_XCAT + (size_t)NB*NKX;
static constexpr size_t WS_ATT1  = WS_PART + (size_t)16*NB*2048;     // 16 k-splits
static constexpr size_t WS_WT    = WS_ATT1 + (size_t)NB*NP*NA;
// WS end = WS_WT + 3072*2048 = 10,754,944 floats (~43 MB)

// ---------------- kernels ----------------

// stable descending argsort of 32 lengths + caps gather + int ws + float outs
__global__ void k_sort(const int* __restrict__ cap, const int* __restrict__ clen,
                       float* __restrict__ out, int* __restrict__ wsi) {
    __shared__ int slen[NB], ssid[NB];
    int i = threadIdx.x;
    if (i < NB) slen[i] = clen[i];
    __syncthreads();
    if (i < NB) {
        int li = slen[i], r = 0;
        for (int j = 0; j < NB; j++) {
            int lj = slen[j];
            if (lj > li || (lj == li && j < i)) r++;
        }
        ssid[r] = i;
    }
    __syncthreads();
    if (i < NB) {
        int src = ssid[i];
        wsi[i] = src;                       // sidx
        int L = slen[src];
        wsi[NB + i] = L - 1;                // dec_len
        out[OUT_LEN + i]  = (float)L;
        out[OUT_SIDX + i] = (float)src;
        for (int tt = 0; tt < NT; tt++) {
            int tok = cap[tt * NB + src];
            wsi[2 * NB + i * NT + tt] = tok;
            out[OUT_CAPS + i * NT + tt] = (float)tok;
        }
    }
}

// mean over 196 pixels of sorted enc
__global__ void k_mean(const float* __restrict__ feat, const int* __restrict__ wsi,
                       float* __restrict__ mean) {
    int g = blockIdx.x * 256 + threadIdx.x;   // 65536 = 32*2048
    int b = g >> 11, d = g & 2047;
    const float* base = feat + (size_t)wsi[b] * (NP * NDE) + d;
    float s = 0.f;
    for (int p = 0; p < NP; p++) s += base[(size_t)p * NDE];
    mean[(size_t)b * NDE + d] = s * (1.0f / 196.0f);
}

// h0 = mean@Wh0+bh0 ; c0 = mean@Wc0+bc0
__global__ void k_h0c0(const float* __restrict__ mean, const float* __restrict__ Wh0,
                       const float* __restrict__ bh0, const float* __restrict__ Wc0,
                       const float* __restrict__ bc0, float* __restrict__ h,
                       float* __restrict__ c) {
    int g = blockIdx.x * 256 + threadIdx.x;   // 32768
    int b = g >> 10, r = g & 1023, which = r >> 9, j = r & 511;
    const float* W = which ? Wc0 : Wh0;
    const float* mb = mean + (size_t)b * NDE;
    float acc = which ? bc0[j] : bh0[j];
    for (int d = 0; d < NDE; d++) acc = fmaf(mb[d], W[(size_t)d * NH + j], acc);
    (which ? c : h)[(size_t)b * NH + j] = acc;
}

// WT[k][j] = Wih[j][k] (k<2560) else Whh[j][k-2560]  -> [3072][2048]
__global__ void k_transpose(const float* __restrict__ Wih, const float* __restrict__ Whh,
                            float* __restrict__ WT) {
    __shared__ float s[32][33];
    int k0 = blockIdx.x * 32, j0 = blockIdx.y * 32;
    int tx = threadIdx.x & 31, ty = threadIdx.x >> 5;  // ty 0..7
    #pragma unroll
    for (int i = 0; i < 4; i++) {
        int jj = ty * 4 + i;
        int j = j0 + jj, k = k0 + tx;
        float v = (k < 2560) ? Wih[(size_t)j * 2560 + k]
                             : Whh[(size_t)j * 512 + (k - 2560)];
        s[jj][tx] = v;
    }
    __syncthreads();
    #pragma unroll
    for (int i = 0; i < 4; i++) {
        int kk = ty * 4 + i;
        WT[(size_t)(k0 + kk) * 2048 + j0 + tx] = s[tx][kk];
    }
}

// att1 = enc @ Wea + bea : M=6272 (b*196+p), N=512, K=2048
// 64x128 tile, 256 threads, 4x8 micro-tile
__global__ __launch_bounds__(256) void k_att1(const float* __restrict__ feat,
                                              const float* __restrict__ Wea,
                                              const float* __restrict__ bea,
                                              const int* __restrict__ wsi,
                                              float* __restrict__ att1) {
    __shared__ float As[16][64];
    __shared__ float Bs[16][128];
    __shared__ int grow[64];
    int m0 = blockIdx.x * 64, n0 = blockIdx.y * 128;
    int tid = threadIdx.x;
    if (tid < 64) {
        int m = m0 + tid;
        int b = m / 196;
        int p = m - b * 196;
        grow[tid] = wsi[b] * 196 + p;
    }
    __syncthreads();
    float acc[4][8];
    #pragma unroll
    for (int i = 0; i < 4; i++)
        #pragma unroll
        for (int j = 0; j < 8; j++) acc[i][j] = 0.f;

    int am = tid >> 2, ak = (tid & 3) * 4;
    int bk = tid >> 4, bn = (tid & 15) * 8;
    int tx = tid & 15, ty = tid >> 4;

    for (int k0 = 0; k0 < NDE; k0 += 16) {
        float4 av = *(const float4*)(feat + (size_t)grow[am] * NDE + k0 + ak);
        As[ak + 0][am] = av.x; As[ak + 1][am] = av.y;
        As[ak + 2][am] = av.z; As[ak + 3][am] = av.w;
        const float* bsrc = Wea + (size_t)(k0 + bk) * NA + n0 + bn;
        float4 bv0 = *(const float4*)(bsrc);
        float4 bv1 = *(const float4*)(bsrc + 4);
        *(float4*)(&Bs[bk][bn])     = bv0;
        *(float4*)(&Bs[bk][bn + 4]) = bv1;
        __syncthreads();
        #pragma unroll
        for (int k = 0; k < 16; k++) {
            float4 a4  = *(const float4*)(&As[k][ty * 4]);
            float4 b40 = *(const float4*)(&Bs[k][tx * 8]);
            float4 b41 = *(const float4*)(&Bs[k][tx * 8 + 4]);
            float av4[4] = {a4.x, a4.y, a4.z, a4.w};
            float bv8[8] = {b40.x, b40.y, b40.z, b40.w, b41.x, b41.y, b41.z, b41.w};
            #pragma unroll
            for (int i = 0; i < 4; i++)
                #pragma unroll
                for (int j = 0; j < 8; j++)
                    acc[i][j] = fmaf(av4[i], bv8[j], acc[i][j]);
        }
        __syncthreads();
    }
    float be[8];
    #pragma unroll
    for (int j = 0; j < 8; j++) be[j] = bea[n0 + tx * 8 + j];
    #pragma unroll
    for (int i = 0; i < 4; i++) {
        int m = m0 + ty * 4 + i;
        float* dst = att1 + (size_t)m * NA + n0 + tx * 8;
        float4 o0, o1;
        o0.x = acc[i][0] + be[0]; o0.y = acc[i][1] + be[1];
        o0.z = acc[i][2] + be[2]; o0.w = acc[i][3] + be[3];
        o1.x = acc[i][4] + be[4]; o1.y = acc[i][5] + be[5];
        o1.z = acc[i][6] + be[6]; o1.w = acc[i][7] + be[7];
        *(float4*)(dst)     = o0;
        *(float4*)(dst + 4) = o1;
    }
}

// per-step K1: att2 + e-scores + softmax + alpha out + xcat emb/h parts
__global__ __launch_bounds__(256) void k_attn(const float* __restrict__ emb,
        const float* __restrict__ Wda, const float* __restrict__ bda,
        const float* __restrict__ Wfa, const float* __restrict__ bfa,
        const int* __restrict__ wsi, const float* __restrict__ h,
        const float* __restrict__ att1, float* __restrict__ alpha_ws,
        float* __restrict__ xcat, float* __restrict__ out, int t) {
    int b = blockIdx.x, tid = threadIdx.x;
    __shared__ float s_att2[512], s_wfa[512], s_e[196];
    __shared__ float sred[256];
    const float* hb = h + (size_t)b * NH;
    int tok = wsi[2 * NB + b * NT + t];
    for (int r = tid; r < 512; r += 256) {
        xcat[(size_t)b * NKX + r]        = emb[(size_t)tok * NE + r];
        xcat[(size_t)b * NKX + 2560 + r] = hb[r];
        s_wfa[r] = Wfa[r];
        float a = bda[r];
        for (int k = 0; k < NH; k++) a = fmaf(hb[k], Wda[(size_t)k * NA + r], a);
        s_att2[r] = a;
    }
    __syncthreads();
    int wid = tid >> 6, lane = tid & 63;
    for (int p = wid; p < NP; p += 4) {
        const float* base = att1 + ((size_t)b * NP + p) * NA;
        float part = 0.f;
        for (int a = lane; a < NA; a += 64) {
            float x = base[a] + s_att2[a];
            part = fmaf(x > 0.f ? x : 0.f, s_wfa[a], part);
        }
        #pragma unroll
        for (int off = 32; off > 0; off >>= 1) part += __shfl_down(part, off);
        if (lane == 0) s_e[p] = part + bfa[0];
    }
    __syncthreads();
    sred[tid] = (tid < NP) ? s_e[tid] : -1e30f;
    __syncthreads();
    for (int s = 128; s > 0; s >>= 1) {
        if (tid < s) sred[tid] = fmaxf(sred[tid], sred[tid + s]);
        __syncthreads();
    }
    float mx = sred[0];
    __syncthreads();
    float ev = (tid < NP) ? expf(s_e[tid] - mx) : 0.f;
    sred[tid] = ev;
    __syncthreads();
    for (int s = 128; s > 0; s >>= 1) {
        if (tid < s) sred[tid] += sred[tid + s];
        __syncthreads();
    }
    float inv = 1.f / sred[0];
    if (tid < NP) {
        float a = ev * inv;
        alpha_ws[(size_t)b * NP + tid] = a;
        int active = wsi[NB + b] > t;
        out[OUT_ALPHA + ((size_t)b * NTD + t) * NP + tid] = active ? a : 0.f;
    }
}

// per-step K2: awe (alpha-weighted enc) and gate, writes xcat[512:2560)
__global__ __launch_bounds__(256) void k_awegate(const float* __restrict__ feat,
        const float* __restrict__ Wfb, const float* __restrict__ bfb,
        const int* __restrict__ wsi, const float* __restrict__ h,
        const float* __restrict__ alpha_ws, float* __restrict__ xcat) {
    int d = blockIdx.x * 256 + threadIdx.x;   // 0..2047
    int b0 = blockIdx.y * 2;
    float aw0 = 0.f, aw1 = 0.f;
    {
        const float* base = feat + (size_t)wsi[b0] * (NP * NDE) + d;
        const float* al = alpha_ws + (size_t)b0 * NP;
        for (int p = 0; p < NP; p++) aw0 = fmaf(al[p], base[(size_t)p * NDE], aw0);
    }
    {
        const float* base = feat + (size_t)wsi[b0 + 1] * (NP * NDE) + d;
        const float* al = alpha_ws + (size_t)(b0 + 1) * NP;
        for (int p = 0; p < NP; p++) aw1 = fmaf(al[p], base[(size_t)p * NDE], aw1);
    }
    float g0 = bfb[d], g1 = g0;
    const float* h0p = h + (size_t)b0 * NH;
    const float* h1p = h + (size_t)(b0 + 1) * NH;
    for (int k = 0; k < NH; k++) {
        float wv = Wfb[(size_t)k * NDE + d];
        g0 = fmaf(h0p[k], wv, g0);
        g1 = fmaf(h1p[k], wv, g1);
    }
    g0 = 1.f / (1.f + expf(-g0));
    g1 = 1.f / (1.f + expf(-g1));
    xcat[(size_t)b0 * NKX + 512 + d]       = g0 * aw0;
    xcat[(size_t)(b0 + 1) * NKX + 512 + d] = g1 * aw1;
}

// per-step K3: gates partials: part[ks][b][2048] = X[b][kr] @ WT[kr][2048]
__global__ __launch_bounds__(256) void k_gates(const float* __restrict__ WT,
        const float* __restrict__ xcat, float* __restrict__ part) {
    int n  = blockIdx.x * 256 + threadIdx.x;  // 0..2047
    int ks = blockIdx.y;                      // 0..15
    int b0 = blockIdx.z * 16;
    float acc[16];
    #pragma unroll
    for (int i = 0; i < 16; i++) acc[i] = 0.f;
    int kbeg = ks * 192, kend = kbeg + 192;
    for (int k = kbeg; k < kend; k++) {
        float w = WT[(size_t)k * 2048 + n];
        #pragma unroll
        for (int i = 0; i < 16; i++)
            acc[i] = fmaf(xcat[(size_t)(b0 + i) * NKX + k], w, acc[i]);
    }
    #pragma unroll
    for (int i = 0; i < 16; i++)
        part[((size_t)ks * NB + b0 + i) * 2048 + n] = acc[i];
}

// per-step K4: reduce partials + biases, LSTM pointwise, masked h/c update
__global__ void k_lstm(const float* __restrict__ part, const float* __restrict__ bih,
                       const float* __restrict__ bhh, const int* __restrict__ wsi,
                       float* __restrict__ h, float* __restrict__ c, int t) {
    int g = blockIdx.x * 256 + threadIdx.x;   // 16384
    int b = g >> 9, j = g & 511;
    float v[4];
    #pragma unroll
    for (int q = 0; q < 4; q++) {
        int idx = q * 512 + j;
        float s = bih[idx] + bhh[idx];
        #pragma unroll
        for (int ks = 0; ks < 16; ks++)
            s += part[((size_t)ks * NB + b) * 2048 + idx];
        v[q] = s;
    }
    float iv = 1.f / (1.f + expf(-v[0]));
    float fv = 1.f / (1.f + expf(-v[1]));
    float gv = tanhf(v[2]);
    float ov = 1.f / (1.f + expf(-v[3]));
    if (wsi[NB + b] > t) {
        float cn = fv * c[(size_t)b * NH + j] + iv * gv;
        c[(size_t)b * NH + j] = cn;
        h[(size_t)b * NH + j] = ov * tanhf(cn);
    }
}

// per-step K5: preds = h_new @ Wout + bout (masked); 16 b per thread
__global__ __launch_bounds__(256) void k_preds(const float* __restrict__ Wout,
        const float* __restrict__ bout, const float* __restrict__ h,
        const int* __restrict__ wsi, float* __restrict__ out, int t) {
    int n = blockIdx.x * 256 + threadIdx.x;
    if (n >= NV) return;
    int b0 = blockIdx.y * 16;
    float acc[16];
    float bz = bout[n];
    #pragma unroll
    for (int i = 0; i < 16; i++) acc[i] = bz;
    for (int k = 0; k < NH; k++) {
        float w = Wout[(size_t)k * NV + n];
        #pragma unroll
        for (int i = 0; i < 16; i++)
            acc[i] = fmaf(h[(size_t)(b0 + i) * NH + k], w, acc[i]);
    }
    #pragma unroll
    for (int i = 0; i < 16; i++) {
        int b = b0 + i;
        int active = wsi[NB + b] > t;
        out[OUT_PRED + ((size_t)b * NTD + t) * NV + n] = active ? acc[i] : 0.f;
    }
}

// ---------------- launch ----------------
extern "C" void kernel_launch(void* const* d_in, const int* in_sizes, int n_in,
                              void* d_out, int out_size, void* d_ws, size_t ws_size,
                              hipStream_t stream) {
    (void)in_sizes; (void)n_in; (void)out_size; (void)ws_size;
    const float* feat     = (const float*)d_in[0];
    const int*   captions = (const int*)d_in[1];
    const int*   clen     = (const int*)d_in[2];
    const float* emb      = (const float*)d_in[3];
    const float* Wea      = (const float*)d_in[4];
    const float* bea      = (const float*)d_in[5];
    const float* Wda      = (const float*)d_in[6];
    const float* bda      = (const float*)d_in[7];
    const float* Wfa      = (const float*)d_in[8];
    const float* bfa      = (const float*)d_in[9];
    const float* Wih      = (const float*)d_in[10];
    const float* bih      = (const float*)d_in[11];
    const float* Whh      = (const float*)d_in[12];
    const float* bhh      = (const float*)d_in[13];
    const float* Wh0      = (const float*)d_in[14];
    const float* bh0      = (const float*)d_in[15];
    const float* Wc0      = (const float*)d_in[16];
    const float* bc0      = (const float*)d_in[17];
    const float* Wfb      = (const float*)d_in[18];
    const float* bfb      = (const float*)d_in[19];
    const float* Wout     = (const float*)d_in[20];
    const float* bout     = (const float*)d_in[21];
    float* out = (float*)d_out;
    int*   wsi = (int*)d_ws;
    float* wsf = (float*)d_ws;

    k_sort<<<1, 64, 0, stream>>>(captions, clen, out, wsi);
    k_mean<<<256, 256, 0, stream>>>(feat, wsi, wsf + WS_MEAN);
    k_h0c0<<<128, 256, 0, stream>>>(wsf + WS_MEAN, Wh0, bh0, Wc0, bc0,
                                    wsf + WS_H, wsf + WS_C);
    k_transpose<<<dim3(96, 64), 256, 0, stream>>>(Wih, Whh, wsf + WS_WT);
    k_att1<<<dim3(98, 4), 256, 0, stream>>>(feat, Wea, bea, wsi, wsf + WS_ATT1);

    for (int t = 0; t < NTD; t++) {
        k_attn<<<32, 256, 0, stream>>>(emb, Wda, bda, Wfa, bfa, wsi, wsf + WS_H,
                                       wsf + WS_ATT1, wsf + WS_ALPHA,
                                       wsf + WS_XCAT, out, t);
        k_awegate<<<dim3(8, 16), 256, 0, stream>>>(feat, Wfb, bfb, wsi, wsf + WS_H,
                                                   wsf + WS_ALPHA, wsf + WS_XCAT);
        k_gates<<<dim3(8, 16, 2), 256, 0, stream>>>(wsf + WS_WT, wsf + WS_XCAT,
                                                    wsf + WS_PART);
        k_lstm<<<64, 256, 0, stream>>>(wsf + WS_PART, bih, bhh, wsi,
                                       wsf + WS_H, wsf + WS_C, t);
        k_preds<<<dim3(118, 2), 256, 0, stream>>>(Wout, bout, wsf + WS_H, wsi, out, t);
    }
}

// Round 2
// 2692.722 us; speedup vs baseline: 2.4083x; 2.4083x over previous
//
#include <hip/hip_runtime.h>
#include <cstdint>
#include <cstddef>

// ---------------- problem constants ----------------
static constexpr int NB  = 32;      // batch
static constexpr int NT  = 22;      // caption length T
static constexpr int NP  = 196;     // pixels 14*14
static constexpr int NDE = 2048;    // encoder dim
static constexpr int NE  = 512;     // embed dim
static constexpr int NH  = 512;     // hidden
static constexpr int NA  = 512;     // attention dim
static constexpr int NV  = 30000;   // vocab
static constexpr int NTD = 20;      // Tdec = T-2
static constexpr int NKX = 3072;    // E + DE + H (concat x | h)

// ---------------- output offsets (floats) ----------------
static constexpr size_t OUT_PRED  = 0;
static constexpr size_t OUT_ALPHA = (size_t)NB*NTD*NV;            // 19,200,000
static constexpr size_t OUT_CAPS  = OUT_ALPHA + (size_t)NB*NTD*NP;// 19,325,440
static constexpr size_t OUT_LEN   = OUT_CAPS + (size_t)NB*NT;     // 19,326,144
static constexpr size_t OUT_SIDX  = OUT_LEN + NB;                 // 19,326,176

// ---------------- ws layout (float offsets) ----------------
// int region: [0,32) sidx | [32,64) declen | [64,768) caps_i
static constexpr size_t WS_H     = 768;
static constexpr size_t WS_C     = 17152;
static constexpr size_t WS_MEAN  = 33536;
static constexpr size_t WS_ALPHA = 99072;
static constexpr size_t WS_ATT2  = 105344;
static constexpr size_t WS_XCATB = 121728;    // bf16 [32][3072]
static constexpr size_t WS_ATT1B = 170880;    // bf16 [6272][512]
static constexpr size_t WS_ENCB  = 1776512;   // bf16 [32][196][2048]
static constexpr size_t WS_W2B   = 8199040;   // bf16 [2048][3072]
static constexpr size_t WS_WDAT  = 11344768;  // bf16 [512][512]   (WdaT[n][k])
static constexpr size_t WS_WEAT  = 11475840;  // bf16 [512][2048]  (WeaT[n][k])
static constexpr size_t WS_WOUTT = 12000128;  // bf16 [30000][512] (WoutT[n][k])
static constexpr size_t WS_WFBB  = 19680128;  // bf16 [512][2048]
// end = 20,204,416 floats ~= 77.1 MB

// ---------------- MFMA types & helpers ----------------
typedef __attribute__((ext_vector_type(8))) short bf16x8;
typedef __attribute__((ext_vector_type(4))) float f32x4;
#define MFMA16(a,b,c) __builtin_amdgcn_mfma_f32_16x16x32_bf16(a,b,c,0,0,0)

__device__ __forceinline__ float bf2f(unsigned short u) {
    return __uint_as_float(((unsigned)u) << 16);
}
__device__ __forceinline__ unsigned short f2bf(float f) {
    unsigned u = __float_as_uint(f);
    u += 0x7FFF + ((u >> 16) & 1);      // RTNE
    return (unsigned short)(u >> 16);
}
__device__ __forceinline__ float sigm(float x) { return 1.f / (1.f + expf(-x)); }

// ---------------- prelude kernels ----------------

__global__ void k_sort(const int* __restrict__ cap, const int* __restrict__ clen,
                       float* __restrict__ out, int* __restrict__ wsi) {
    __shared__ int slen[NB], ssid[NB];
    int i = threadIdx.x;
    if (i < NB) slen[i] = clen[i];
    __syncthreads();
    if (i < NB) {
        int li = slen[i], r = 0;
        for (int j = 0; j < NB; j++) {
            int lj = slen[j];
            if (lj > li || (lj == li && j < i)) r++;
        }
        ssid[r] = i;
    }
    __syncthreads();
    if (i < NB) {
        int src = ssid[i];
        wsi[i] = src;
        int L = slen[src];
        wsi[NB + i] = L - 1;
        out[OUT_LEN + i]  = (float)L;
        out[OUT_SIDX + i] = (float)src;
        for (int tt = 0; tt < NT; tt++) {
            int tok = cap[tt * NB + src];
            wsi[2 * NB + i * NT + tt] = tok;
            out[OUT_CAPS + i * NT + tt] = (float)tok;
        }
    }
}

// sorted-gather feat -> enc bf16, plus per-(b,d) mean
__global__ void k_prep(const float* __restrict__ feat, const int* __restrict__ wsi,
                       unsigned short* __restrict__ encb, float* __restrict__ mean) {
    int g = blockIdx.x * 256 + threadIdx.x;   // 65536 = 32*2048
    int b = g >> 11, d = g & 2047;
    const float* src = feat + (size_t)wsi[b] * (NP * NDE) + d;
    unsigned short* dst = encb + (size_t)b * (NP * NDE) + d;
    float s = 0.f;
    for (int p = 0; p < NP; p++) {
        float v = src[(size_t)p * NDE];
        s += v;
        dst[(size_t)p * NDE] = f2bf(v);
    }
    mean[(size_t)b * NDE + d] = s * (1.0f / 196.0f);
}

__global__ void k_h0c0(const float* __restrict__ mean, const float* __restrict__ Wh0,
                       const float* __restrict__ bh0, const float* __restrict__ Wc0,
                       const float* __restrict__ bc0, float* __restrict__ h,
                       float* __restrict__ c, unsigned short* __restrict__ xcatb) {
    int g = blockIdx.x * 256 + threadIdx.x;   // 32768
    int b = g >> 10, r = g & 1023, which = r >> 9, j = r & 511;
    const float* W = which ? Wc0 : Wh0;
    const float* mb = mean + (size_t)b * NDE;
    float acc = which ? bc0[j] : bh0[j];
    for (int d = 0; d < NDE; d++) acc = fmaf(mb[d], W[(size_t)d * NH + j], acc);
    if (which) {
        c[(size_t)b * NH + j] = acc;
    } else {
        h[(size_t)b * NH + j] = acc;
        xcatb[(size_t)b * NKX + 2560 + j] = f2bf(acc);
    }
}

// W2b[n][k] = bf16( k<2560 ? Wih[n][k] : Whh[n][k-2560] )
__global__ void k_w2b(const float* __restrict__ Wih, const float* __restrict__ Whh,
                      unsigned short* __restrict__ W2b) {
    int k = blockIdx.x * 256 + threadIdx.x;   // 0..3071
    int n = blockIdx.y;                       // 0..2047
    float v = (k < 2560) ? Wih[(size_t)n * 2560 + k]
                         : Whh[(size_t)n * 512 + (k - 2560)];
    W2b[(size_t)n * NKX + k] = f2bf(v);
}

// fp32 [R][C] -> bf16 [C][R] (R multiple of 32; C bounds-checked)
__global__ void k_trbf(const float* __restrict__ src, unsigned short* __restrict__ dst,
                       int R, int C) {
    __shared__ float s[32][33];
    int c0 = blockIdx.x * 32, r0 = blockIdx.y * 32;
    int tx = threadIdx.x & 31, ty = threadIdx.x >> 5;  // ty 0..7
    #pragma unroll
    for (int i = 0; i < 4; i++) {
        int rr = ty * 4 + i;
        int cc = c0 + tx;
        s[rr][tx] = (cc < C) ? src[(size_t)(r0 + rr) * C + cc] : 0.f;
    }
    __syncthreads();
    #pragma unroll
    for (int i = 0; i < 4; i++) {
        int cc = ty * 4 + i;
        int cg = c0 + cc;
        if (cg < C) dst[(size_t)cg * R + r0 + tx] = f2bf(s[tx][cc]);
    }
}

__global__ void k_wfbb(const float* __restrict__ Wfb, unsigned short* __restrict__ Wfbb) {
    int g = blockIdx.x * 256 + threadIdx.x;   // 1048576
    Wfbb[g] = f2bf(Wfb[g]);
}

// att1 = enc @ Wea + bea  (MFMA bf16): M=6272, N=512, K=2048 -> att1b bf16
__global__ __launch_bounds__(256) void k_att1(const unsigned short* __restrict__ encb,
        const unsigned short* __restrict__ WeaT, const float* __restrict__ bea,
        unsigned short* __restrict__ att1b) {
    __shared__ unsigned short As[64 * 40];    // 64 m x 32 k, stride 40
    int m0 = blockIdx.x * 64;
    int nb = blockIdx.y * 256;
    int tid = threadIdx.x;
    int w = tid >> 6, lane = tid & 63, ln = lane & 15, quad = lane >> 4;
    int nbase = nb + w * 64;
    f32x4 acc[4][4] = {};
    int sm = tid >> 2, sc = tid & 3;
    for (int k0 = 0; k0 < NDE; k0 += 32) {
        bf16x8 v = *(const bf16x8*)(encb + (size_t)(m0 + sm) * NDE + k0 + sc * 8);
        __syncthreads();
        *(bf16x8*)(&As[sm * 40 + sc * 8]) = v;
        __syncthreads();
        bf16x8 a[4], bb[4];
        #pragma unroll
        for (int i = 0; i < 4; i++)
            a[i] = *(const bf16x8*)(&As[(i * 16 + ln) * 40 + quad * 8]);
        #pragma unroll
        for (int j = 0; j < 4; j++)
            bb[j] = *(const bf16x8*)(WeaT + (size_t)(nbase + j * 16 + ln) * NDE + k0 + quad * 8);
        #pragma unroll
        for (int i = 0; i < 4; i++)
            #pragma unroll
            for (int j = 0; j < 4; j++)
                acc[i][j] = MFMA16(a[i], bb[j], acc[i][j]);
    }
    #pragma unroll
    for (int i = 0; i < 4; i++)
        #pragma unroll
        for (int j = 0; j < 4; j++) {
            int n = nbase + j * 16 + ln;
            float be = bea[n];
            #pragma unroll
            for (int r = 0; r < 4; r++) {
                int m = m0 + i * 16 + quad * 4 + r;
                att1b[(size_t)m * NA + n] = f2bf(acc[i][j][r] + be);
            }
        }
}

// att2 = h @ Wda + bda (MFMA), one 64-wide n-tile per block (8 tiles total)
__device__ __forceinline__ void att2_tile(int bi, const unsigned short* __restrict__ xcatb,
        const unsigned short* __restrict__ WdaT, const float* __restrict__ bda,
        float* __restrict__ att2, int tid) {
    int w = tid >> 6, lane = tid & 63, ln = lane & 15, quad = lane >> 4;
    int n = bi * 64 + w * 16 + ln;
    f32x4 acc0 = {0.f, 0.f, 0.f, 0.f}, acc1 = {0.f, 0.f, 0.f, 0.f};
    for (int k0 = 0; k0 < NH; k0 += 32) {
        bf16x8 bfr = *(const bf16x8*)(WdaT + (size_t)n * NH + k0 + quad * 8);
        bf16x8 a0 = *(const bf16x8*)(xcatb + (size_t)ln * NKX + 2560 + k0 + quad * 8);
        bf16x8 a1 = *(const bf16x8*)(xcatb + (size_t)(16 + ln) * NKX + 2560 + k0 + quad * 8);
        acc0 = MFMA16(a0, bfr, acc0);
        acc1 = MFMA16(a1, bfr, acc1);
    }
    float bd = bda[n];
    #pragma unroll
    for (int r = 0; r < 4; r++) {
        int b0r = quad * 4 + r;
        att2[(size_t)b0r * NA + n]        = acc0[r] + bd;
        att2[(size_t)(16 + b0r) * NA + n] = acc1[r] + bd;
    }
}

__global__ __launch_bounds__(256) void k_att2k(const unsigned short* __restrict__ xcatb,
        const unsigned short* __restrict__ WdaT, const float* __restrict__ bda,
        float* __restrict__ att2) {
    att2_tile(blockIdx.x, xcatb, WdaT, bda, att2, threadIdx.x);
}

// ---------------- per-step kernels ----------------

// KA: e-scores + softmax + alpha + xcat emb slot
__global__ __launch_bounds__(256) void k_attn(const float* __restrict__ emb,
        const float* __restrict__ Wfa, const float* __restrict__ bfa,
        const int* __restrict__ wsi, const float* __restrict__ att2,
        const unsigned short* __restrict__ att1b, float* __restrict__ alpha_ws,
        unsigned short* __restrict__ xcatb, float* __restrict__ out, int t) {
    int b = blockIdx.x, tid = threadIdx.x;
    int lane = tid & 63;
    __shared__ float s_e[NP];
    __shared__ float sred[256];
    int tok = wsi[2 * NB + b * NT + t];
    xcatb[(size_t)b * NKX + tid]       = f2bf(emb[(size_t)tok * NE + tid]);
    xcatb[(size_t)b * NKX + tid + 256] = f2bf(emb[(size_t)tok * NE + tid + 256]);
    float a2r[8], wfr[8];
    #pragma unroll
    for (int u = 0; u < 8; u++) {
        a2r[u] = att2[(size_t)b * NA + lane * 8 + u];
        wfr[u] = Wfa[lane * 8 + u];
    }
    int w = tid >> 6;
    for (int p = w; p < NP; p += 4) {
        bf16x8 a8 = *(const bf16x8*)(att1b + ((size_t)b * NP + p) * NA + lane * 8);
        float part = 0.f;
        #pragma unroll
        for (int u = 0; u < 8; u++) {
            float x = bf2f((unsigned short)a8[u]) + a2r[u];
            part = fmaf(fmaxf(x, 0.f), wfr[u], part);
        }
        #pragma unroll
        for (int off = 32; off > 0; off >>= 1) part += __shfl_down(part, off);
        if (lane == 0) s_e[p] = part + bfa[0];
    }
    __syncthreads();
    sred[tid] = (tid < NP) ? s_e[tid] : -1e30f;
    __syncthreads();
    for (int s = 128; s > 0; s >>= 1) {
        if (tid < s) sred[tid] = fmaxf(sred[tid], sred[tid + s]);
        __syncthreads();
    }
    float mx = sred[0];
    __syncthreads();
    float ev = (tid < NP) ? expf(s_e[tid] - mx) : 0.f;
    sred[tid] = ev;
    __syncthreads();
    for (int s = 128; s > 0; s >>= 1) {
        if (tid < s) sred[tid] += sred[tid + s];
        __syncthreads();
    }
    float inv = 1.f / sred[0];
    if (tid < NP) {
        float a = ev * inv;
        alpha_ws[(size_t)b * NP + tid] = a;
        int active = wsi[NB + b] > t;
        out[OUT_ALPHA + ((size_t)b * NTD + t) * NP + tid] = active ? a : 0.f;
    }
}

// KB: awe + gate -> xcat[512:2560) bf16
__global__ __launch_bounds__(256) void k_awegate(const unsigned short* __restrict__ encb,
        const unsigned short* __restrict__ Wfbb, const float* __restrict__ bfb,
        const float* __restrict__ h, const float* __restrict__ alpha_ws,
        unsigned short* __restrict__ xcatb) {
    int d = blockIdx.x * 256 + threadIdx.x;   // 0..2047
    int b0 = blockIdx.y * 2;
    const unsigned short* e0 = encb + (size_t)b0 * (NP * NDE) + d;
    const unsigned short* e1 = e0 + (size_t)NP * NDE;
    const float* al0 = alpha_ws + (size_t)b0 * NP;
    const float* al1 = al0 + NP;
    float aw0 = 0.f, aw1 = 0.f;
    for (int p = 0; p < NP; p++) {
        aw0 = fmaf(al0[p], bf2f(e0[(size_t)p * NDE]), aw0);
        aw1 = fmaf(al1[p], bf2f(e1[(size_t)p * NDE]), aw1);
    }
    float g0 = bfb[d], g1 = g0;
    const float* h0p = h + (size_t)b0 * NH;
    const float* h1p = h0p + NH;
    for (int k = 0; k < NH; k++) {
        float wv = bf2f(Wfbb[(size_t)k * NDE + d]);
        g0 = fmaf(h0p[k], wv, g0);
        g1 = fmaf(h1p[k], wv, g1);
    }
    xcatb[(size_t)b0 * NKX + 512 + d]       = f2bf(sigm(g0) * aw0);
    xcatb[(size_t)(b0 + 1) * NKX + 512 + d] = f2bf(sigm(g1) * aw1);
}

// KC: gates GEMM (MFMA, k-split over 4 waves) + LDS reduce + LSTM pointwise
__global__ __launch_bounds__(256) void k_gateslstm(const unsigned short* __restrict__ W2b,
        unsigned short* __restrict__ xcatb, const float* __restrict__ bih,
        const float* __restrict__ bhh, const int* __restrict__ wsi,
        float* __restrict__ h, float* __restrict__ c, int t) {
    __shared__ float red[4][8][4][64];        // 32 KB
    int tid = threadIdx.x;
    int w = tid >> 6, lane = tid & 63, ln = lane & 15, quad = lane >> 4;
    int j0 = blockIdx.x * 16;
    f32x4 acc[8] = {};
    int kb = w * 768;
    for (int ks = 0; ks < 24; ks++) {
        int k = kb + ks * 32 + quad * 8;
        bf16x8 a0 = *(const bf16x8*)(xcatb + (size_t)ln * NKX + k);
        bf16x8 a1 = *(const bf16x8*)(xcatb + (size_t)(16 + ln) * NKX + k);
        #pragma unroll
        for (int q = 0; q < 4; q++) {
            bf16x8 bq = *(const bf16x8*)(W2b + (size_t)(q * 512 + j0 + ln) * NKX + k);
            acc[q * 2]     = MFMA16(a0, bq, acc[q * 2]);
            acc[q * 2 + 1] = MFMA16(a1, bq, acc[q * 2 + 1]);
        }
    }
    #pragma unroll
    for (int f = 0; f < 8; f++)
        #pragma unroll
        for (int r = 0; r < 4; r++)
            red[w][f][r][lane] = acc[f][r];
    __syncthreads();
    for (int v = tid; v < 512; v += 256) {
        int b = v >> 4, j = v & 15;
        int mh = b >> 4, row = b & 15, reg = row & 3;
        int lq = ((row >> 2) << 4) | j;
        float g4[4];
        #pragma unroll
        for (int q = 0; q < 4; q++) {
            int n = q * 512 + j0 + j;
            float s = bih[n] + bhh[n];
            #pragma unroll
            for (int w2 = 0; w2 < 4; w2++) s += red[w2][q * 2 + mh][reg][lq];
            g4[q] = s;
        }
        if (wsi[NB + b] > t) {
            int jg = j0 + j;
            float cn = sigm(g4[1]) * c[(size_t)b * NH + jg] + sigm(g4[0]) * tanhf(g4[2]);
            float hn = sigm(g4[3]) * tanhf(cn);
            c[(size_t)b * NH + jg] = cn;
            h[(size_t)b * NH + jg] = hn;
            xcatb[(size_t)b * NKX + 2560 + jg] = f2bf(hn);
        }
    }
}

// KD: preds = h @ Wout + bout (MFMA, masked) + fused att2 for next step
__global__ __launch_bounds__(256) void k_predsatt2(const unsigned short* __restrict__ WoutT,
        const float* __restrict__ bout, const unsigned short* __restrict__ xcatb,
        const unsigned short* __restrict__ WdaT, const float* __restrict__ bda,
        const int* __restrict__ wsi, float* __restrict__ att2,
        float* __restrict__ out, int t) {
    int tid = threadIdx.x;
    if (blockIdx.x >= 469) {
        att2_tile(blockIdx.x - 469, xcatb, WdaT, bda, att2, tid);
        return;
    }
    int w = tid >> 6, lane = tid & 63, ln = lane & 15, quad = lane >> 4;
    int n = blockIdx.x * 64 + w * 16 + ln;
    int nc = (n < NV) ? n : (NV - 1);
    f32x4 acc0 = {0.f, 0.f, 0.f, 0.f}, acc1 = {0.f, 0.f, 0.f, 0.f};
    for (int k0 = 0; k0 < NH; k0 += 32) {
        bf16x8 bfr = *(const bf16x8*)(WoutT + (size_t)nc * NH + k0 + quad * 8);
        bf16x8 a0 = *(const bf16x8*)(xcatb + (size_t)ln * NKX + 2560 + k0 + quad * 8);
        bf16x8 a1 = *(const bf16x8*)(xcatb + (size_t)(16 + ln) * NKX + 2560 + k0 + quad * 8);
        acc0 = MFMA16(a0, bfr, acc0);
        acc1 = MFMA16(a1, bfr, acc1);
    }
    if (n >= NV) return;
    float bo = bout[n];
    #pragma unroll
    for (int r = 0; r < 4; r++) {
        int b0r = quad * 4 + r;
        int act0 = wsi[NB + b0r] > t;
        out[OUT_PRED + ((size_t)b0r * NTD + t) * NV + n] = act0 ? (acc0[r] + bo) : 0.f;
        int b1 = 16 + b0r;
        int act1 = wsi[NB + b1] > t;
        out[OUT_PRED + ((size_t)b1 * NTD + t) * NV + n] = act1 ? (acc1[r] + bo) : 0.f;
    }
}

// ---------------- launch ----------------
extern "C" void kernel_launch(void* const* d_in, const int* in_sizes, int n_in,
                              void* d_out, int out_size, void* d_ws, size_t ws_size,
                              hipStream_t stream) {
    (void)in_sizes; (void)n_in; (void)out_size; (void)ws_size;
    const float* feat     = (const float*)d_in[0];
    const int*   captions = (const int*)d_in[1];
    const int*   clen     = (const int*)d_in[2];
    const float* emb      = (const float*)d_in[3];
    const float* Wea      = (const float*)d_in[4];
    const float* bea      = (const float*)d_in[5];
    const float* Wda      = (const float*)d_in[6];
    const float* bda      = (const float*)d_in[7];
    const float* Wfa      = (const float*)d_in[8];
    const float* bfa      = (const float*)d_in[9];
    const float* Wih      = (const float*)d_in[10];
    const float* bih      = (const float*)d_in[11];
    const float* Whh      = (const float*)d_in[12];
    const float* bhh      = (const float*)d_in[13];
    const float* Wh0      = (const float*)d_in[14];
    const float* bh0      = (const float*)d_in[15];
    const float* Wc0      = (const float*)d_in[16];
    const float* bc0      = (const float*)d_in[17];
    const float* Wfb      = (const float*)d_in[18];
    const float* bfb      = (const float*)d_in[19];
    const float* Wout     = (const float*)d_in[20];
    const float* bout     = (const float*)d_in[21];
    float* out = (float*)d_out;
    int*   wsi = (int*)d_ws;
    float* wsf = (float*)d_ws;

    float* W_h     = wsf + WS_H;
    float* W_c     = wsf + WS_C;
    float* W_mean  = wsf + WS_MEAN;
    float* W_alpha = wsf + WS_ALPHA;
    float* W_att2  = wsf + WS_ATT2;
    unsigned short* W_xcatb = (unsigned short*)(wsf + WS_XCATB);
    unsigned short* W_att1b = (unsigned short*)(wsf + WS_ATT1B);
    unsigned short* W_encb  = (unsigned short*)(wsf + WS_ENCB);
    unsigned short* W_w2b   = (unsigned short*)(wsf + WS_W2B);
    unsigned short* W_wdaT  = (unsigned short*)(wsf + WS_WDAT);
    unsigned short* W_weaT  = (unsigned short*)(wsf + WS_WEAT);
    unsigned short* W_woutT = (unsigned short*)(wsf + WS_WOUTT);
    unsigned short* W_wfbb  = (unsigned short*)(wsf + WS_WFBB);

    k_sort<<<1, 64, 0, stream>>>(captions, clen, out, wsi);
    k_prep<<<256, 256, 0, stream>>>(feat, wsi, W_encb, W_mean);
    k_h0c0<<<128, 256, 0, stream>>>(W_mean, Wh0, bh0, Wc0, bc0, W_h, W_c, W_xcatb);
    k_w2b<<<dim3(12, 2048), 256, 0, stream>>>(Wih, Whh, W_w2b);
    k_trbf<<<dim3(16, 16), 256, 0, stream>>>(Wda, W_wdaT, 512, 512);
    k_trbf<<<dim3(16, 64), 256, 0, stream>>>(Wea, W_weaT, 2048, 512);
    k_trbf<<<dim3(938, 16), 256, 0, stream>>>(Wout, W_woutT, 512, 30000);
    k_wfbb<<<4096, 256, 0, stream>>>(Wfb, W_wfbb);
    k_att1<<<dim3(98, 2), 256, 0, stream>>>(W_encb, W_weaT, bea, W_att1b);
    k_att2k<<<8, 256, 0, stream>>>(W_xcatb, W_wdaT, bda, W_att2);

    for (int t = 0; t < NTD; t++) {
        k_attn<<<32, 256, 0, stream>>>(emb, Wfa, bfa, wsi, W_att2, W_att1b,
                                       W_alpha, W_xcatb, out, t);
        k_awegate<<<dim3(8, 16), 256, 0, stream>>>(W_encb, W_wfbb, bfb, W_h,
                                                   W_alpha, W_xcatb);
        k_gateslstm<<<32, 256, 0, stream>>>(W_w2b, W_xcatb, bih, bhh, wsi,
                                            W_h, W_c, t);
        k_predsatt2<<<477, 256, 0, stream>>>(W_woutT, bout, W_xcatb, W_wdaT, bda,
                                             wsi, W_att2, out, t);
    }
}

// Round 3
// 2257.625 us; speedup vs baseline: 2.8725x; 1.1927x over previous
//
#include <hip/hip_runtime.h>
#include <cstdint>
#include <cstddef>

// ---------------- problem constants ----------------
static constexpr int NB  = 32;      // batch
static constexpr int NT  = 22;      // caption length T
static constexpr int NP  = 196;     // pixels 14*14
static constexpr int NDE = 2048;    // encoder dim
static constexpr int NE  = 512;     // embed dim
static constexpr int NH  = 512;     // hidden
static constexpr int NA  = 512;     // attention dim
static constexpr int NV  = 30000;   // vocab
static constexpr int NTD = 20;      // Tdec = T-2
static constexpr int NKX = 3072;    // E + DE + H (concat x | h)

// ---------------- output offsets (floats) ----------------
static constexpr size_t OUT_PRED  = 0;
static constexpr size_t OUT_ALPHA = (size_t)NB*NTD*NV;            // 19,200,000
static constexpr size_t OUT_CAPS  = OUT_ALPHA + (size_t)NB*NTD*NP;// 19,325,440
static constexpr size_t OUT_LEN   = OUT_CAPS + (size_t)NB*NT;     // 19,326,144
static constexpr size_t OUT_SIDX  = OUT_LEN + NB;                 // 19,326,176

// ---------------- ws layout (float offsets) ----------------
// int region: [0,32) sidx | [32,64) declen | [64,768) caps_i
static constexpr size_t WS_H     = 768;
static constexpr size_t WS_C     = 17152;
static constexpr size_t WS_MEAN  = 33536;
static constexpr size_t WS_ALPHA = 99072;
static constexpr size_t WS_ATT2  = 105344;
static constexpr size_t WS_XCATB = 121728;    // bf16 [32][3072]
static constexpr size_t WS_ATT1B = 170880;    // bf16 [6272][512]
static constexpr size_t WS_ENCB  = 1776512;   // bf16 [32][196][2048]
static constexpr size_t WS_W2B   = 8199040;   // bf16 [2048][3072]
static constexpr size_t WS_WDAT  = 11344768;  // bf16 [512][512]   (WdaT[n][k])
static constexpr size_t WS_WEAT  = 11475840;  // bf16 [512][2048]  (WeaT[n][k])
static constexpr size_t WS_WOUTT = 12000128;  // bf16 [30000][512] (WoutT[n][k])
static constexpr size_t WS_WFBT  = 19680128;  // bf16 [2048][512]  (WfbT[d][k])
static constexpr size_t WS_MEANB = 20204416;  // bf16 [32][2048]
static constexpr size_t WS_WH0T  = 20237184;  // bf16 [512][2048]
static constexpr size_t WS_WC0T  = 20761472;  // bf16 [512][2048]
static constexpr size_t WS_HIST  = 21285760;  // bf16 [640][512] (h history, m=t*32+b)
// end = 21,449,600 floats ~= 81.8 MB

// ---------------- MFMA types & helpers ----------------
typedef __attribute__((ext_vector_type(8))) short bf16x8;
typedef __attribute__((ext_vector_type(4))) float f32x4;
#define MFMA16(a,b,c) __builtin_amdgcn_mfma_f32_16x16x32_bf16(a,b,c,0,0,0)

__device__ __forceinline__ float bf2f(unsigned short u) {
    return __uint_as_float(((unsigned)u) << 16);
}
__device__ __forceinline__ unsigned short f2bf(float f) {
    unsigned u = __float_as_uint(f);
    u += 0x7FFF + ((u >> 16) & 1);      // RTNE
    return (unsigned short)(u >> 16);
}
__device__ __forceinline__ float sigm(float x) { return 1.f / (1.f + expf(-x)); }

// ---------------- prelude kernels ----------------

__global__ void k_sort(const int* __restrict__ cap, const int* __restrict__ clen,
                       float* __restrict__ out, int* __restrict__ wsi) {
    __shared__ int slen[NB], ssid[NB];
    int i = threadIdx.x;
    if (i < NB) slen[i] = clen[i];
    __syncthreads();
    if (i < NB) {
        int li = slen[i], r = 0;
        for (int j = 0; j < NB; j++) {
            int lj = slen[j];
            if (lj > li || (lj == li && j < i)) r++;
        }
        ssid[r] = i;
    }
    __syncthreads();
    if (i < NB) {
        int src = ssid[i];
        wsi[i] = src;
        int L = slen[src];
        wsi[NB + i] = L - 1;
        out[OUT_LEN + i]  = (float)L;
        out[OUT_SIDX + i] = (float)src;
        for (int tt = 0; tt < NT; tt++) {
            int tok = cap[tt * NB + src];
            wsi[2 * NB + i * NT + tt] = tok;
            out[OUT_CAPS + i * NT + tt] = (float)tok;
        }
    }
}

// sorted-gather feat -> enc bf16, plus per-(b,d) mean (fp32 + bf16)
__global__ void k_prep(const float* __restrict__ feat, const int* __restrict__ wsi,
                       unsigned short* __restrict__ encb, float* __restrict__ mean,
                       unsigned short* __restrict__ meanb) {
    int g = blockIdx.x * 256 + threadIdx.x;   // 65536 = 32*2048
    int b = g >> 11, d = g & 2047;
    const float* src = feat + (size_t)wsi[b] * (NP * NDE) + d;
    unsigned short* dst = encb + (size_t)b * (NP * NDE) + d;
    float s = 0.f;
    for (int p = 0; p < NP; p++) {
        float v = src[(size_t)p * NDE];
        s += v;
        dst[(size_t)p * NDE] = f2bf(v);
    }
    float m = s * (1.0f / 196.0f);
    mean[(size_t)b * NDE + d] = m;
    meanb[(size_t)b * NDE + d] = f2bf(m);
}

// h0/c0 via MFMA: M=32, N=512 each; 16 blocks (8 h-tiles, 8 c-tiles)
__global__ __launch_bounds__(256) void k_h0c0m(const unsigned short* __restrict__ meanb,
        const unsigned short* __restrict__ WH0T, const unsigned short* __restrict__ WC0T,
        const float* __restrict__ bh0, const float* __restrict__ bc0,
        float* __restrict__ h, float* __restrict__ c, unsigned short* __restrict__ xcatb) {
    int tid = threadIdx.x;
    int w = tid >> 6, lane = tid & 63, ln = lane & 15, quad = lane >> 4;
    int which = blockIdx.x >> 3;
    int n = (blockIdx.x & 7) * 64 + w * 16 + ln;
    const unsigned short* WT = which ? WC0T : WH0T;
    f32x4 acc0 = {0.f, 0.f, 0.f, 0.f}, acc1 = {0.f, 0.f, 0.f, 0.f};
    for (int k0 = 0; k0 < NDE; k0 += 32) {
        bf16x8 bfr = *(const bf16x8*)(WT + (size_t)n * NDE + k0 + quad * 8);
        bf16x8 a0 = *(const bf16x8*)(meanb + (size_t)ln * NDE + k0 + quad * 8);
        bf16x8 a1 = *(const bf16x8*)(meanb + (size_t)(16 + ln) * NDE + k0 + quad * 8);
        acc0 = MFMA16(a0, bfr, acc0);
        acc1 = MFMA16(a1, bfr, acc1);
    }
    float bias = which ? bc0[n] : bh0[n];
    #pragma unroll
    for (int r = 0; r < 4; r++) {
        int b0r = quad * 4 + r;
        float v0 = acc0[r] + bias, v1 = acc1[r] + bias;
        if (which) {
            c[(size_t)b0r * NH + n] = v0;
            c[(size_t)(16 + b0r) * NH + n] = v1;
        } else {
            h[(size_t)b0r * NH + n] = v0;
            h[(size_t)(16 + b0r) * NH + n] = v1;
            xcatb[(size_t)b0r * NKX + 2560 + n] = f2bf(v0);
            xcatb[(size_t)(16 + b0r) * NKX + 2560 + n] = f2bf(v1);
        }
    }
}

// W2b[n][k] = bf16( k<2560 ? Wih[n][k] : Whh[n][k-2560] )
__global__ void k_w2b(const float* __restrict__ Wih, const float* __restrict__ Whh,
                      unsigned short* __restrict__ W2b) {
    int k = blockIdx.x * 256 + threadIdx.x;   // 0..3071
    int n = blockIdx.y;                       // 0..2047
    float v = (k < 2560) ? Wih[(size_t)n * 2560 + k]
                         : Whh[(size_t)n * 512 + (k - 2560)];
    W2b[(size_t)n * NKX + k] = f2bf(v);
}

// fp32 [R][C] -> bf16 [C][R] (R multiple of 32; C bounds-checked)
__global__ void k_trbf(const float* __restrict__ src, unsigned short* __restrict__ dst,
                       int R, int C) {
    __shared__ float s[32][33];
    int c0 = blockIdx.x * 32, r0 = blockIdx.y * 32;
    int tx = threadIdx.x & 31, ty = threadIdx.x >> 5;  // ty 0..7
    #pragma unroll
    for (int i = 0; i < 4; i++) {
        int rr = ty * 4 + i;
        int cc = c0 + tx;
        s[rr][tx] = (cc < C) ? src[(size_t)(r0 + rr) * C + cc] : 0.f;
    }
    __syncthreads();
    #pragma unroll
    for (int i = 0; i < 4; i++) {
        int cc = ty * 4 + i;
        int cg = c0 + cc;
        if (cg < C) dst[(size_t)cg * R + r0 + tx] = f2bf(s[tx][cc]);
    }
}

// att1 = enc @ Wea + bea  (MFMA bf16): M=6272, N=512, K=2048 -> att1b bf16
__global__ __launch_bounds__(256) void k_att1(const unsigned short* __restrict__ encb,
        const unsigned short* __restrict__ WeaT, const float* __restrict__ bea,
        unsigned short* __restrict__ att1b) {
    __shared__ unsigned short As[64 * 40];    // 64 m x 32 k, stride 40
    int m0 = blockIdx.x * 64;
    int nb = blockIdx.y * 256;
    int tid = threadIdx.x;
    int w = tid >> 6, lane = tid & 63, ln = lane & 15, quad = lane >> 4;
    int nbase = nb + w * 64;
    f32x4 acc[4][4] = {};
    int sm = tid >> 2, sc = tid & 3;
    for (int k0 = 0; k0 < NDE; k0 += 32) {
        bf16x8 v = *(const bf16x8*)(encb + (size_t)(m0 + sm) * NDE + k0 + sc * 8);
        __syncthreads();
        *(bf16x8*)(&As[sm * 40 + sc * 8]) = v;
        __syncthreads();
        bf16x8 a[4], bb[4];
        #pragma unroll
        for (int i = 0; i < 4; i++)
            a[i] = *(const bf16x8*)(&As[(i * 16 + ln) * 40 + quad * 8]);
        #pragma unroll
        for (int j = 0; j < 4; j++)
            bb[j] = *(const bf16x8*)(WeaT + (size_t)(nbase + j * 16 + ln) * NDE + k0 + quad * 8);
        #pragma unroll
        for (int i = 0; i < 4; i++)
            #pragma unroll
            for (int j = 0; j < 4; j++)
                acc[i][j] = MFMA16(a[i], bb[j], acc[i][j]);
    }
    #pragma unroll
    for (int i = 0; i < 4; i++)
        #pragma unroll
        for (int j = 0; j < 4; j++) {
            int n = nbase + j * 16 + ln;
            float be = bea[n];
            #pragma unroll
            for (int r = 0; r < 4; r++) {
                int m = m0 + i * 16 + quad * 4 + r;
                att1b[(size_t)m * NA + n] = f2bf(acc[i][j][r] + be);
            }
        }
}

// att2 = h @ Wda + bda (MFMA), one 64-wide n-tile per block (8 blocks)
__global__ __launch_bounds__(256) void k_att2k(const unsigned short* __restrict__ xcatb,
        const unsigned short* __restrict__ WdaT, const float* __restrict__ bda,
        float* __restrict__ att2) {
    int tid = threadIdx.x;
    int w = tid >> 6, lane = tid & 63, ln = lane & 15, quad = lane >> 4;
    int n = blockIdx.x * 64 + w * 16 + ln;
    f32x4 acc0 = {0.f, 0.f, 0.f, 0.f}, acc1 = {0.f, 0.f, 0.f, 0.f};
    for (int k0 = 0; k0 < NH; k0 += 32) {
        bf16x8 bfr = *(const bf16x8*)(WdaT + (size_t)n * NH + k0 + quad * 8);
        bf16x8 a0 = *(const bf16x8*)(xcatb + (size_t)ln * NKX + 2560 + k0 + quad * 8);
        bf16x8 a1 = *(const bf16x8*)(xcatb + (size_t)(16 + ln) * NKX + 2560 + k0 + quad * 8);
        acc0 = MFMA16(a0, bfr, acc0);
        acc1 = MFMA16(a1, bfr, acc1);
    }
    float bd = bda[n];
    #pragma unroll
    for (int r = 0; r < 4; r++) {
        int b0r = quad * 4 + r;
        att2[(size_t)b0r * NA + n]        = acc0[r] + bd;
        att2[(size_t)(16 + b0r) * NA + n] = acc1[r] + bd;
    }
}

// ---------------- per-step kernels ----------------

// KA: e-scores + softmax + alpha + xcat emb slot
__global__ __launch_bounds__(256) void k_attn(const float* __restrict__ emb,
        const float* __restrict__ Wfa, const float* __restrict__ bfa,
        const int* __restrict__ wsi, const float* __restrict__ att2,
        const unsigned short* __restrict__ att1b, float* __restrict__ alpha_ws,
        unsigned short* __restrict__ xcatb, float* __restrict__ out, int t) {
    int b = blockIdx.x, tid = threadIdx.x;
    int lane = tid & 63;
    __shared__ float s_e[NP];
    __shared__ float sred[256];
    int tok = wsi[2 * NB + b * NT + t];
    xcatb[(size_t)b * NKX + tid]       = f2bf(emb[(size_t)tok * NE + tid]);
    xcatb[(size_t)b * NKX + tid + 256] = f2bf(emb[(size_t)tok * NE + tid + 256]);
    float a2r[8], wfr[8];
    #pragma unroll
    for (int u = 0; u < 8; u++) {
        a2r[u] = att2[(size_t)b * NA + lane * 8 + u];
        wfr[u] = Wfa[lane * 8 + u];
    }
    int w = tid >> 6;
    for (int p = w; p < NP; p += 4) {
        bf16x8 a8 = *(const bf16x8*)(att1b + ((size_t)b * NP + p) * NA + lane * 8);
        float part = 0.f;
        #pragma unroll
        for (int u = 0; u < 8; u++) {
            float x = bf2f((unsigned short)a8[u]) + a2r[u];
            part = fmaf(fmaxf(x, 0.f), wfr[u], part);
        }
        #pragma unroll
        for (int off = 32; off > 0; off >>= 1) part += __shfl_down(part, off);
        if (lane == 0) s_e[p] = part + bfa[0];
    }
    __syncthreads();
    sred[tid] = (tid < NP) ? s_e[tid] : -1e30f;
    __syncthreads();
    for (int s = 128; s > 0; s >>= 1) {
        if (tid < s) sred[tid] = fmaxf(sred[tid], sred[tid + s]);
        __syncthreads();
    }
    float mx = sred[0];
    __syncthreads();
    float ev = (tid < NP) ? expf(s_e[tid] - mx) : 0.f;
    sred[tid] = ev;
    __syncthreads();
    for (int s = 128; s > 0; s >>= 1) {
        if (tid < s) sred[tid] += sred[tid + s];
        __syncthreads();
    }
    float inv = 1.f / sred[0];
    if (tid < NP) {
        float a = ev * inv;
        alpha_ws[(size_t)b * NP + tid] = a;
        int active = wsi[NB + b] > t;
        out[OUT_ALPHA + ((size_t)b * NTD + t) * NP + tid] = active ? a : 0.f;
    }
}

// KB: awe + gate -> xcat[512:2560); grid (8, 32): one b per block-row
__global__ __launch_bounds__(256) void k_awegate(const unsigned short* __restrict__ encb,
        const unsigned short* __restrict__ WfbT, const float* __restrict__ bfb,
        const float* __restrict__ h, const float* __restrict__ alpha_ws,
        unsigned short* __restrict__ xcatb) {
    int tid = threadIdx.x;
    int b = blockIdx.y;
    int d = blockIdx.x * 256 + tid;           // 0..2047
    __shared__ float s_h[NH];
    __shared__ float s_al[NP];
    s_h[tid] = h[(size_t)b * NH + tid];
    s_h[tid + 256] = h[(size_t)b * NH + 256 + tid];
    if (tid < NP) s_al[tid] = alpha_ws[(size_t)b * NP + tid];
    __syncthreads();
    const unsigned short* e = encb + (size_t)b * (NP * NDE) + d;
    float aw = 0.f;
    #pragma unroll 4
    for (int p = 0; p < NP; p++)
        aw = fmaf(s_al[p], bf2f(e[(size_t)p * NDE]), aw);
    float g = bfb[d];
    const unsigned short* wf = WfbT + (size_t)d * NH;
    for (int k0 = 0; k0 < NH; k0 += 8) {
        bf16x8 wv = *(const bf16x8*)(wf + k0);
        #pragma unroll
        for (int u = 0; u < 8; u++)
            g = fmaf(s_h[k0 + u], bf2f((unsigned short)wv[u]), g);
    }
    xcatb[(size_t)b * NKX + 512 + d] = f2bf(sigm(g) * aw);
}

// KC: gates GEMM (MFMA, k-split over 8 waves) + LDS reduce + LSTM pointwise + hist
__global__ __launch_bounds__(512) void k_gateslstm(const unsigned short* __restrict__ W2b,
        unsigned short* __restrict__ xcatb, const float* __restrict__ bih,
        const float* __restrict__ bhh, const int* __restrict__ wsi,
        float* __restrict__ h, float* __restrict__ c,
        unsigned short* __restrict__ histb, int t) {
    __shared__ float red[8][8][4][64];        // 64 KB
    int tid = threadIdx.x;
    int w = tid >> 6, lane = tid & 63, ln = lane & 15, quad = lane >> 4;
    int j0 = blockIdx.x * 16;
    f32x4 acc[8] = {};
    int kb = w * 384;
    for (int ks = 0; ks < 12; ks++) {
        int k = kb + ks * 32 + quad * 8;
        bf16x8 a0 = *(const bf16x8*)(xcatb + (size_t)ln * NKX + k);
        bf16x8 a1 = *(const bf16x8*)(xcatb + (size_t)(16 + ln) * NKX + k);
        #pragma unroll
        for (int q = 0; q < 4; q++) {
            bf16x8 bq = *(const bf16x8*)(W2b + (size_t)(q * 512 + j0 + ln) * NKX + k);
            acc[q * 2]     = MFMA16(a0, bq, acc[q * 2]);
            acc[q * 2 + 1] = MFMA16(a1, bq, acc[q * 2 + 1]);
        }
    }
    #pragma unroll
    for (int f = 0; f < 8; f++)
        #pragma unroll
        for (int r = 0; r < 4; r++)
            red[w][f][r][lane] = acc[f][r];
    __syncthreads();
    if (tid < 512) {
        int v = tid;
        int b = v >> 4, j = v & 15;
        int mh = b >> 4, row = b & 15, reg = row & 3;
        int lq = ((row >> 2) << 4) | j;
        float g4[4];
        #pragma unroll
        for (int q = 0; q < 4; q++) {
            int n = q * 512 + j0 + j;
            float s = bih[n] + bhh[n];
            #pragma unroll
            for (int w2 = 0; w2 < 8; w2++) s += red[w2][q * 2 + mh][reg][lq];
            g4[q] = s;
        }
        int jg = j0 + j;
        int active = wsi[NB + b] > t;
        float hv;
        if (active) {
            float cn = sigm(g4[1]) * c[(size_t)b * NH + jg] + sigm(g4[0]) * tanhf(g4[2]);
            hv = sigm(g4[3]) * tanhf(cn);
            c[(size_t)b * NH + jg] = cn;
            h[(size_t)b * NH + jg] = hv;
            xcatb[(size_t)b * NKX + 2560 + jg] = f2bf(hv);
        } else {
            hv = h[(size_t)b * NH + jg];
        }
        histb[((size_t)t * NB + b) * NH + jg] = f2bf(hv);
    }
}

// FINAL: preds for all steps = hist @ Wout + bout (masked)
// grid (469, 2); block handles 64 n x 320 m
__global__ __launch_bounds__(256) void k_preds_all(const unsigned short* __restrict__ WoutT,
        const float* __restrict__ bout, const unsigned short* __restrict__ histb,
        const int* __restrict__ wsi, float* __restrict__ out) {
    int tid = threadIdx.x;
    int w = tid >> 6, lane = tid & 63, ln = lane & 15, quad = lane >> 4;
    int n = blockIdx.x * 64 + w * 16 + ln;
    int nc = (n < NV) ? n : (NV - 1);
    int m0 = blockIdx.y * 320;
    f32x4 acc[20] = {};
    for (int k0 = 0; k0 < NH; k0 += 32) {
        bf16x8 bfr = *(const bf16x8*)(WoutT + (size_t)nc * NH + k0 + quad * 8);
        #pragma unroll
        for (int i = 0; i < 20; i++) {
            bf16x8 a = *(const bf16x8*)(histb + (size_t)(m0 + i * 16 + ln) * NH + k0 + quad * 8);
            acc[i] = MFMA16(a, bfr, acc[i]);
        }
    }
    if (n >= NV) return;
    float bo = bout[n];
    #pragma unroll
    for (int i = 0; i < 20; i++) {
        #pragma unroll
        for (int r = 0; r < 4; r++) {
            int m = m0 + i * 16 + quad * 4 + r;
            int tt = m >> 5, b = m & 31;
            int active = wsi[NB + b] > tt;
            out[OUT_PRED + ((size_t)b * NTD + tt) * NV + n] = active ? (acc[i][r] + bo) : 0.f;
        }
    }
}

// ---------------- launch ----------------
extern "C" void kernel_launch(void* const* d_in, const int* in_sizes, int n_in,
                              void* d_out, int out_size, void* d_ws, size_t ws_size,
                              hipStream_t stream) {
    (void)in_sizes; (void)n_in; (void)out_size; (void)ws_size;
    const float* feat     = (const float*)d_in[0];
    const int*   captions = (const int*)d_in[1];
    const int*   clen     = (const int*)d_in[2];
    const float* emb      = (const float*)d_in[3];
    const float* Wea      = (const float*)d_in[4];
    const float* bea      = (const float*)d_in[5];
    const float* Wda      = (const float*)d_in[6];
    const float* bda      = (const float*)d_in[7];
    const float* Wfa      = (const float*)d_in[8];
    const float* bfa      = (const float*)d_in[9];
    const float* Wih      = (const float*)d_in[10];
    const float* bih      = (const float*)d_in[11];
    const float* Whh      = (const float*)d_in[12];
    const float* bhh      = (const float*)d_in[13];
    const float* Wh0      = (const float*)d_in[14];
    const float* bh0      = (const float*)d_in[15];
    const float* Wc0      = (const float*)d_in[16];
    const float* bc0      = (const float*)d_in[17];
    const float* Wfb      = (const float*)d_in[18];
    const float* bfb      = (const float*)d_in[19];
    const float* Wout     = (const float*)d_in[20];
    const float* bout     = (const float*)d_in[21];
    float* out = (float*)d_out;
    int*   wsi = (int*)d_ws;
    float* wsf = (float*)d_ws;

    float* W_h     = wsf + WS_H;
    float* W_c     = wsf + WS_C;
    float* W_mean  = wsf + WS_MEAN;
    float* W_alpha = wsf + WS_ALPHA;
    float* W_att2  = wsf + WS_ATT2;
    unsigned short* W_xcatb = (unsigned short*)(wsf + WS_XCATB);
    unsigned short* W_att1b = (unsigned short*)(wsf + WS_ATT1B);
    unsigned short* W_encb  = (unsigned short*)(wsf + WS_ENCB);
    unsigned short* W_w2b   = (unsigned short*)(wsf + WS_W2B);
    unsigned short* W_wdaT  = (unsigned short*)(wsf + WS_WDAT);
    unsigned short* W_weaT  = (unsigned short*)(wsf + WS_WEAT);
    unsigned short* W_woutT = (unsigned short*)(wsf + WS_WOUTT);
    unsigned short* W_wfbT  = (unsigned short*)(wsf + WS_WFBT);
    unsigned short* W_meanb = (unsigned short*)(wsf + WS_MEANB);
    unsigned short* W_wh0T  = (unsigned short*)(wsf + WS_WH0T);
    unsigned short* W_wc0T  = (unsigned short*)(wsf + WS_WC0T);
    unsigned short* W_hist  = (unsigned short*)(wsf + WS_HIST);

    k_sort<<<1, 64, 0, stream>>>(captions, clen, out, wsi);
    k_prep<<<256, 256, 0, stream>>>(feat, wsi, W_encb, W_mean, W_meanb);
    k_trbf<<<dim3(16, 64), 256, 0, stream>>>(Wh0, W_wh0T, 2048, 512);
    k_trbf<<<dim3(16, 64), 256, 0, stream>>>(Wc0, W_wc0T, 2048, 512);
    k_h0c0m<<<16, 256, 0, stream>>>(W_meanb, W_wh0T, W_wc0T, bh0, bc0,
                                    W_h, W_c, W_xcatb);
    k_w2b<<<dim3(12, 2048), 256, 0, stream>>>(Wih, Whh, W_w2b);
    k_trbf<<<dim3(16, 16), 256, 0, stream>>>(Wda, W_wdaT, 512, 512);
    k_trbf<<<dim3(16, 64), 256, 0, stream>>>(Wea, W_weaT, 2048, 512);
    k_trbf<<<dim3(938, 16), 256, 0, stream>>>(Wout, W_woutT, 512, 30000);
    k_trbf<<<dim3(64, 16), 256, 0, stream>>>(Wfb, W_wfbT, 512, 2048);
    k_att1<<<dim3(98, 2), 256, 0, stream>>>(W_encb, W_weaT, bea, W_att1b);
    k_att2k<<<8, 256, 0, stream>>>(W_xcatb, W_wdaT, bda, W_att2);

    for (int t = 0; t < NTD; t++) {
        k_attn<<<32, 256, 0, stream>>>(emb, Wfa, bfa, wsi, W_att2, W_att1b,
                                       W_alpha, W_xcatb, out, t);
        k_awegate<<<dim3(8, 32), 256, 0, stream>>>(W_encb, W_wfbT, bfb, W_h,
                                                   W_alpha, W_xcatb);
        k_gateslstm<<<32, 512, 0, stream>>>(W_w2b, W_xcatb, bih, bhh, wsi,
                                            W_h, W_c, W_hist, t);
        k_att2k<<<8, 256, 0, stream>>>(W_xcatb, W_wdaT, bda, W_att2);
    }
    k_preds_all<<<dim3(469, 2), 256, 0, stream>>>(W_woutT, bout, W_hist, wsi, out);
}

// Round 4
// 2169.149 us; speedup vs baseline: 2.9896x; 1.0408x over previous
//
#include <hip/hip_runtime.h>
#include <cstdint>
#include <cstddef>

// ---------------- problem constants ----------------
static constexpr int NB  = 32;      // batch
static constexpr int NT  = 22;      // caption length T
static constexpr int NP  = 196;     // pixels 14*14
static constexpr int NDE = 2048;    // encoder dim
static constexpr int NE  = 512;     // embed dim
static constexpr int NH  = 512;     // hidden
static constexpr int NA  = 512;     // attention dim
static constexpr int NV  = 30000;   // vocab
static constexpr int NTD = 20;      // Tdec = T-2
static constexpr int NKX = 3072;    // E + DE + H (concat x | h)

// ---------------- output offsets (floats) ----------------
static constexpr size_t OUT_PRED  = 0;
static constexpr size_t OUT_ALPHA = (size_t)NB*NTD*NV;            // 19,200,000
static constexpr size_t OUT_CAPS  = OUT_ALPHA + (size_t)NB*NTD*NP;// 19,325,440
static constexpr size_t OUT_LEN   = OUT_CAPS + (size_t)NB*NT;     // 19,326,144
static constexpr size_t OUT_SIDX  = OUT_LEN + NB;                 // 19,326,176

// ---------------- ws layout (float offsets) ----------------
// int region: [0,32) sidx | [32,64) declen | [64,768) caps_i
static constexpr size_t WS_H     = 768;
static constexpr size_t WS_C     = 17152;
static constexpr size_t WS_MEAN  = 33536;
static constexpr size_t WS_XCATB = 121728;    // bf16 [32][3072]
static constexpr size_t WS_ATT1B = 170880;    // bf16 [6272][512]
static constexpr size_t WS_ENCB  = 1776512;   // bf16 [32][196][2048]
static constexpr size_t WS_W2B   = 8199040;   // bf16 [2048][3072]
static constexpr size_t WS_WDAT  = 11344768;  // bf16 [512][512]   (WdaT[n][k])
static constexpr size_t WS_WEAT  = 11475840;  // bf16 [512][2048]  (WeaT[n][k])
static constexpr size_t WS_WOUTT = 12000128;  // bf16 [30000][512] (WoutT[n][k])
static constexpr size_t WS_WFBT  = 19680128;  // bf16 [2048][512]  (WfbT[d][k])
static constexpr size_t WS_MEANB = 20204416;  // bf16 [32][2048]
static constexpr size_t WS_WH0T  = 20237184;  // bf16 [512][2048]
static constexpr size_t WS_WC0T  = 20761472;  // bf16 [512][2048]
static constexpr size_t WS_HIST  = 21285760;  // bf16 [640][512] (h history, m=t*32+b)
// end = 21,449,600 floats ~= 81.8 MB

// ---------------- MFMA types & helpers ----------------
typedef __attribute__((ext_vector_type(8))) short bf16x8;
typedef __attribute__((ext_vector_type(4))) float f32x4;
#define MFMA16(a,b,c) __builtin_amdgcn_mfma_f32_16x16x32_bf16(a,b,c,0,0,0)

__device__ __forceinline__ float bf2f(unsigned short u) {
    return __uint_as_float(((unsigned)u) << 16);
}
__device__ __forceinline__ unsigned short f2bf(float f) {
    unsigned u = __float_as_uint(f);
    u += 0x7FFF + ((u >> 16) & 1);      // RTNE
    return (unsigned short)(u >> 16);
}
__device__ __forceinline__ float sigm(float x) { return 1.f / (1.f + expf(-x)); }

// ---------------- prelude kernels ----------------

__global__ void k_sort(const int* __restrict__ cap, const int* __restrict__ clen,
                       float* __restrict__ out, int* __restrict__ wsi) {
    __shared__ int slen[NB], ssid[NB];
    int i = threadIdx.x;
    if (i < NB) slen[i] = clen[i];
    __syncthreads();
    if (i < NB) {
        int li = slen[i], r = 0;
        for (int j = 0; j < NB; j++) {
            int lj = slen[j];
            if (lj > li || (lj == li && j < i)) r++;
        }
        ssid[r] = i;
    }
    __syncthreads();
    if (i < NB) {
        int src = ssid[i];
        wsi[i] = src;
        int L = slen[src];
        wsi[NB + i] = L - 1;
        out[OUT_LEN + i]  = (float)L;
        out[OUT_SIDX + i] = (float)src;
        for (int tt = 0; tt < NT; tt++) {
            int tok = cap[tt * NB + src];
            wsi[2 * NB + i * NT + tt] = tok;
            out[OUT_CAPS + i * NT + tt] = (float)tok;
        }
    }
}

// sorted-gather feat -> enc bf16, plus per-(b,d) mean (fp32 + bf16)
__global__ void k_prep(const float* __restrict__ feat, const int* __restrict__ wsi,
                       unsigned short* __restrict__ encb, float* __restrict__ mean,
                       unsigned short* __restrict__ meanb) {
    int g = blockIdx.x * 256 + threadIdx.x;   // 65536 = 32*2048
    int b = g >> 11, d = g & 2047;
    const float* src = feat + (size_t)wsi[b] * (NP * NDE) + d;
    unsigned short* dst = encb + (size_t)b * (NP * NDE) + d;
    float s = 0.f;
    for (int p = 0; p < NP; p++) {
        float v = src[(size_t)p * NDE];
        s += v;
        dst[(size_t)p * NDE] = f2bf(v);
    }
    float m = s * (1.0f / 196.0f);
    mean[(size_t)b * NDE + d] = m;
    meanb[(size_t)b * NDE + d] = f2bf(m);
}

// h0/c0 via MFMA: M=32, N=512 each; 16 blocks (8 h-tiles, 8 c-tiles)
__global__ __launch_bounds__(256) void k_h0c0m(const unsigned short* __restrict__ meanb,
        const unsigned short* __restrict__ WH0T, const unsigned short* __restrict__ WC0T,
        const float* __restrict__ bh0, const float* __restrict__ bc0,
        float* __restrict__ h, float* __restrict__ c, unsigned short* __restrict__ xcatb) {
    int tid = threadIdx.x;
    int w = tid >> 6, lane = tid & 63, ln = lane & 15, quad = lane >> 4;
    int which = blockIdx.x >> 3;
    int n = (blockIdx.x & 7) * 64 + w * 16 + ln;
    const unsigned short* WT = which ? WC0T : WH0T;
    f32x4 acc0 = {0.f, 0.f, 0.f, 0.f}, acc1 = {0.f, 0.f, 0.f, 0.f};
    for (int k0 = 0; k0 < NDE; k0 += 32) {
        bf16x8 bfr = *(const bf16x8*)(WT + (size_t)n * NDE + k0 + quad * 8);
        bf16x8 a0 = *(const bf16x8*)(meanb + (size_t)ln * NDE + k0 + quad * 8);
        bf16x8 a1 = *(const bf16x8*)(meanb + (size_t)(16 + ln) * NDE + k0 + quad * 8);
        acc0 = MFMA16(a0, bfr, acc0);
        acc1 = MFMA16(a1, bfr, acc1);
    }
    float bias = which ? bc0[n] : bh0[n];
    #pragma unroll
    for (int r = 0; r < 4; r++) {
        int b0r = quad * 4 + r;
        float v0 = acc0[r] + bias, v1 = acc1[r] + bias;
        if (which) {
            c[(size_t)b0r * NH + n] = v0;
            c[(size_t)(16 + b0r) * NH + n] = v1;
        } else {
            h[(size_t)b0r * NH + n] = v0;
            h[(size_t)(16 + b0r) * NH + n] = v1;
            xcatb[(size_t)b0r * NKX + 2560 + n] = f2bf(v0);
            xcatb[(size_t)(16 + b0r) * NKX + 2560 + n] = f2bf(v1);
        }
    }
}

// W2b[n][k] = bf16( k<2560 ? Wih[n][k] : Whh[n][k-2560] )
__global__ void k_w2b(const float* __restrict__ Wih, const float* __restrict__ Whh,
                      unsigned short* __restrict__ W2b) {
    int k = blockIdx.x * 256 + threadIdx.x;   // 0..3071
    int n = blockIdx.y;                       // 0..2047
    float v = (k < 2560) ? Wih[(size_t)n * 2560 + k]
                         : Whh[(size_t)n * 512 + (k - 2560)];
    W2b[(size_t)n * NKX + k] = f2bf(v);
}

// fp32 [R][C] -> bf16 [C][R] (R multiple of 32; C bounds-checked)
__global__ void k_trbf(const float* __restrict__ src, unsigned short* __restrict__ dst,
                       int R, int C) {
    __shared__ float s[32][33];
    int c0 = blockIdx.x * 32, r0 = blockIdx.y * 32;
    int tx = threadIdx.x & 31, ty = threadIdx.x >> 5;  // ty 0..7
    #pragma unroll
    for (int i = 0; i < 4; i++) {
        int rr = ty * 4 + i;
        int cc = c0 + tx;
        s[rr][tx] = (cc < C) ? src[(size_t)(r0 + rr) * C + cc] : 0.f;
    }
    __syncthreads();
    #pragma unroll
    for (int i = 0; i < 4; i++) {
        int cc = ty * 4 + i;
        int cg = c0 + cc;
        if (cg < C) dst[(size_t)cg * R + r0 + tx] = f2bf(s[tx][cc]);
    }
}

// att1 = enc @ Wea + bea  (MFMA bf16): M=6272, N=512, K=2048 -> att1b bf16
__global__ __launch_bounds__(256) void k_att1(const unsigned short* __restrict__ encb,
        const unsigned short* __restrict__ WeaT, const float* __restrict__ bea,
        unsigned short* __restrict__ att1b) {
    __shared__ unsigned short As[64 * 40];    // 64 m x 32 k, stride 40
    int m0 = blockIdx.x * 64;
    int nb = blockIdx.y * 256;
    int tid = threadIdx.x;
    int w = tid >> 6, lane = tid & 63, ln = lane & 15, quad = lane >> 4;
    int nbase = nb + w * 64;
    f32x4 acc[4][4] = {};
    int sm = tid >> 2, sc = tid & 3;
    for (int k0 = 0; k0 < NDE; k0 += 32) {
        bf16x8 v = *(const bf16x8*)(encb + (size_t)(m0 + sm) * NDE + k0 + sc * 8);
        __syncthreads();
        *(bf16x8*)(&As[sm * 40 + sc * 8]) = v;
        __syncthreads();
        bf16x8 a[4], bb[4];
        #pragma unroll
        for (int i = 0; i < 4; i++)
            a[i] = *(const bf16x8*)(&As[(i * 16 + ln) * 40 + quad * 8]);
        #pragma unroll
        for (int j = 0; j < 4; j++)
            bb[j] = *(const bf16x8*)(WeaT + (size_t)(nbase + j * 16 + ln) * NDE + k0 + quad * 8);
        #pragma unroll
        for (int i = 0; i < 4; i++)
            #pragma unroll
            for (int j = 0; j < 4; j++)
                acc[i][j] = MFMA16(a[i], bb[j], acc[i][j]);
    }
    #pragma unroll
    for (int i = 0; i < 4; i++)
        #pragma unroll
        for (int j = 0; j < 4; j++) {
            int n = nbase + j * 16 + ln;
            float be = bea[n];
            #pragma unroll
            for (int r = 0; r < 4; r++) {
                int m = m0 + i * 16 + quad * 4 + r;
                att1b[(size_t)m * NA + n] = f2bf(acc[i][j][r] + be);
            }
        }
}

// ---------------- per-step kernels ----------------

// K1 (fused): att2(h) + scores + softmax + alpha-out + emb gather + awe + gate
// grid (32 b, 4 dgrp) x 512 threads. dgrp blocks duplicate attn work; each
// handles a 512-wide slice of d for awe/gate.
__global__ __launch_bounds__(512) void k_step1(const float* __restrict__ emb,
        const unsigned short* __restrict__ WdaT, const float* __restrict__ bda,
        const float* __restrict__ Wfa, const float* __restrict__ bfa,
        const int* __restrict__ wsi, const float* __restrict__ h,
        const unsigned short* __restrict__ att1b, const unsigned short* __restrict__ encb,
        const unsigned short* __restrict__ WfbT, const float* __restrict__ bfb,
        unsigned short* __restrict__ xcatb, float* __restrict__ out, int t) {
    int b = blockIdx.x, dgrp = blockIdx.y;
    int tid = threadIdx.x, lane = tid & 63;
    __shared__ float s_h[NH];
    __shared__ float s_att2[NA];
    __shared__ float s_e[NP];
    __shared__ float s_al[NP];
    __shared__ float sred[256];

    // A: h -> LDS; emb gather (dgrp 0 only)
    s_h[tid] = h[(size_t)b * NH + tid];
    if (dgrp == 0) {
        int tok = wsi[2 * NB + b * NT + t];
        xcatb[(size_t)b * NKX + tid] = f2bf(emb[(size_t)tok * NE + tid]);
    }
    __syncthreads();

    // B: att2[n=tid] = bda[n] + h . WdaT[n]
    {
        const unsigned short* wr = WdaT + (size_t)tid * NH;
        float a = bda[tid];
        for (int k0 = 0; k0 < NH; k0 += 8) {
            bf16x8 wv = *(const bf16x8*)(wr + k0);
            #pragma unroll
            for (int u = 0; u < 8; u++)
                a = fmaf(s_h[k0 + u], bf2f((unsigned short)wv[u]), a);
        }
        s_att2[tid] = a;
    }
    __syncthreads();

    // C: e-scores over 8 waves
    {
        int wd = tid >> 6;
        float a2r[8], wfr[8];
        #pragma unroll
        for (int u = 0; u < 8; u++) {
            a2r[u] = s_att2[lane * 8 + u];
            wfr[u] = Wfa[lane * 8 + u];
        }
        for (int p = wd; p < NP; p += 8) {
            bf16x8 a8 = *(const bf16x8*)(att1b + ((size_t)b * NP + p) * NA + lane * 8);
            float part = 0.f;
            #pragma unroll
            for (int u = 0; u < 8; u++) {
                float x = bf2f((unsigned short)a8[u]) + a2r[u];
                part = fmaf(fmaxf(x, 0.f), wfr[u], part);
            }
            #pragma unroll
            for (int off = 32; off > 0; off >>= 1) part += __shfl_down(part, off);
            if (lane == 0) s_e[p] = part + bfa[0];
        }
    }
    __syncthreads();

    // D: softmax over 196
    if (tid < 256) sred[tid] = (tid < NP) ? s_e[tid] : -1e30f;
    __syncthreads();
    for (int s = 128; s > 0; s >>= 1) {
        if (tid < s) sred[tid] = fmaxf(sred[tid], sred[tid + s]);
        __syncthreads();
    }
    float mx = sred[0];
    __syncthreads();
    float ev = (tid < NP) ? expf(s_e[tid] - mx) : 0.f;
    if (tid < 256) sred[tid] = ev;
    __syncthreads();
    for (int s = 128; s > 0; s >>= 1) {
        if (tid < s) sred[tid] += sred[tid + s];
        __syncthreads();
    }
    float inv = 1.f / sred[0];
    if (tid < NP) {
        float a = ev * inv;
        s_al[tid] = a;
        if (dgrp == 0) {
            int active = wsi[NB + b] > t;
            out[OUT_ALPHA + ((size_t)b * NTD + t) * NP + tid] = active ? a : 0.f;
        }
    }
    __syncthreads();

    // E: d-slice awe + gate -> xcat[512+d]
    {
        int d = dgrp * 512 + tid;
        const unsigned short* e = encb + (size_t)b * (NP * NDE) + d;
        float aw = 0.f;
        #pragma unroll 4
        for (int p = 0; p < NP; p++)
            aw = fmaf(s_al[p], bf2f(e[(size_t)p * NDE]), aw);
        float g = bfb[d];
        const unsigned short* wf = WfbT + (size_t)d * NH;
        for (int k0 = 0; k0 < NH; k0 += 8) {
            bf16x8 wv = *(const bf16x8*)(wf + k0);
            #pragma unroll
            for (int u = 0; u < 8; u++)
                g = fmaf(s_h[k0 + u], bf2f((unsigned short)wv[u]), g);
        }
        xcatb[(size_t)b * NKX + 512 + d] = f2bf(sigm(g) * aw);
    }
}

// K2: gates GEMM (MFMA, k-split over 8 waves) + LDS reduce + LSTM pointwise + hist
__global__ __launch_bounds__(512) void k_gateslstm(const unsigned short* __restrict__ W2b,
        unsigned short* __restrict__ xcatb, const float* __restrict__ bih,
        const float* __restrict__ bhh, const int* __restrict__ wsi,
        float* __restrict__ h, float* __restrict__ c,
        unsigned short* __restrict__ histb, int t) {
    __shared__ float red[8][8][4][64];        // 64 KB
    int tid = threadIdx.x;
    int w = tid >> 6, lane = tid & 63, ln = lane & 15, quad = lane >> 4;
    int j0 = blockIdx.x * 16;
    f32x4 acc[8] = {};
    int kb = w * 384;
    for (int ks = 0; ks < 12; ks++) {
        int k = kb + ks * 32 + quad * 8;
        bf16x8 a0 = *(const bf16x8*)(xcatb + (size_t)ln * NKX + k);
        bf16x8 a1 = *(const bf16x8*)(xcatb + (size_t)(16 + ln) * NKX + k);
        #pragma unroll
        for (int q = 0; q < 4; q++) {
            bf16x8 bq = *(const bf16x8*)(W2b + (size_t)(q * 512 + j0 + ln) * NKX + k);
            acc[q * 2]     = MFMA16(a0, bq, acc[q * 2]);
            acc[q * 2 + 1] = MFMA16(a1, bq, acc[q * 2 + 1]);
        }
    }
    #pragma unroll
    for (int f = 0; f < 8; f++)
        #pragma unroll
        for (int r = 0; r < 4; r++)
            red[w][f][r][lane] = acc[f][r];
    __syncthreads();
    if (tid < 512) {
        int v = tid;
        int b = v >> 4, j = v & 15;
        int mh = b >> 4, row = b & 15, reg = row & 3;
        int lq = ((row >> 2) << 4) | j;
        float g4[4];
        #pragma unroll
        for (int q = 0; q < 4; q++) {
            int n = q * 512 + j0 + j;
            float s = bih[n] + bhh[n];
            #pragma unroll
            for (int w2 = 0; w2 < 8; w2++) s += red[w2][q * 2 + mh][reg][lq];
            g4[q] = s;
        }
        int jg = j0 + j;
        int active = wsi[NB + b] > t;
        float hv;
        if (active) {
            float cn = sigm(g4[1]) * c[(size_t)b * NH + jg] + sigm(g4[0]) * tanhf(g4[2]);
            hv = sigm(g4[3]) * tanhf(cn);
            c[(size_t)b * NH + jg] = cn;
            h[(size_t)b * NH + jg] = hv;
            xcatb[(size_t)b * NKX + 2560 + jg] = f2bf(hv);
        } else {
            hv = h[(size_t)b * NH + jg];
        }
        histb[((size_t)t * NB + b) * NH + jg] = f2bf(hv);
    }
}

// FINAL: preds = hist @ Wout + bout (masked). grid (118 n-tiles, 10 m-tiles).
// Block: 256 n x 64 m; hist tile staged in LDS (padded stride).
static constexpr int HP = 520;      // padded LDS row stride (bf16 elems)
__global__ __launch_bounds__(256) void k_preds_all(const unsigned short* __restrict__ WoutT,
        const float* __restrict__ bout, const unsigned short* __restrict__ histb,
        const int* __restrict__ wsi, float* __restrict__ out) {
    __shared__ unsigned short s_hist[64 * HP];   // ~66.5 KB
    int tid = threadIdx.x;
    int w = tid >> 6, lane = tid & 63, ln = lane & 15, quad = lane >> 4;
    int n0 = blockIdx.x * 256 + w * 64;
    int m0 = blockIdx.y * 64;
    for (int i = tid; i < 64 * 64; i += 256) {
        int r = i >> 6, cc = i & 63;
        *(bf16x8*)(&s_hist[r * HP + cc * 8]) =
            *(const bf16x8*)(histb + (size_t)(m0 + r) * NH + cc * 8);
    }
    __syncthreads();
    f32x4 acc[4][4] = {};
    for (int k0 = 0; k0 < NH; k0 += 32) {
        bf16x8 bfr[4], afr[4];
        #pragma unroll
        for (int j = 0; j < 4; j++) {
            int n = n0 + j * 16 + ln;
            int nc = (n < NV) ? n : (NV - 1);
            bfr[j] = *(const bf16x8*)(WoutT + (size_t)nc * NH + k0 + quad * 8);
        }
        #pragma unroll
        for (int i = 0; i < 4; i++)
            afr[i] = *(const bf16x8*)(&s_hist[(i * 16 + ln) * HP + k0 + quad * 8]);
        #pragma unroll
        for (int i = 0; i < 4; i++)
            #pragma unroll
            for (int j = 0; j < 4; j++)
                acc[i][j] = MFMA16(afr[i], bfr[j], acc[i][j]);
    }
    #pragma unroll
    for (int j = 0; j < 4; j++) {
        int n = n0 + j * 16 + ln;
        if (n >= NV) continue;
        float bo = bout[n];
        #pragma unroll
        for (int i = 0; i < 4; i++) {
            #pragma unroll
            for (int r = 0; r < 4; r++) {
                int m = m0 + i * 16 + quad * 4 + r;
                int tt = m >> 5, b = m & 31;
                int active = wsi[NB + b] > tt;
                out[OUT_PRED + ((size_t)b * NTD + tt) * NV + n] =
                    active ? (acc[i][j][r] + bo) : 0.f;
            }
        }
    }
}

// ---------------- launch ----------------
extern "C" void kernel_launch(void* const* d_in, const int* in_sizes, int n_in,
                              void* d_out, int out_size, void* d_ws, size_t ws_size,
                              hipStream_t stream) {
    (void)in_sizes; (void)n_in; (void)out_size; (void)ws_size;
    const float* feat     = (const float*)d_in[0];
    const int*   captions = (const int*)d_in[1];
    const int*   clen     = (const int*)d_in[2];
    const float* emb      = (const float*)d_in[3];
    const float* Wea      = (const float*)d_in[4];
    const float* bea      = (const float*)d_in[5];
    const float* Wda      = (const float*)d_in[6];
    const float* bda      = (const float*)d_in[7];
    const float* Wfa      = (const float*)d_in[8];
    const float* bfa      = (const float*)d_in[9];
    const float* Wih      = (const float*)d_in[10];
    const float* bih      = (const float*)d_in[11];
    const float* Whh      = (const float*)d_in[12];
    const float* bhh      = (const float*)d_in[13];
    const float* Wh0      = (const float*)d_in[14];
    const float* bh0      = (const float*)d_in[15];
    const float* Wc0      = (const float*)d_in[16];
    const float* bc0      = (const float*)d_in[17];
    const float* Wfb      = (const float*)d_in[18];
    const float* bfb      = (const float*)d_in[19];
    const float* Wout     = (const float*)d_in[20];
    const float* bout     = (const float*)d_in[21];
    float* out = (float*)d_out;
    int*   wsi = (int*)d_ws;
    float* wsf = (float*)d_ws;

    float* W_h     = wsf + WS_H;
    float* W_c     = wsf + WS_C;
    float* W_mean  = wsf + WS_MEAN;
    unsigned short* W_xcatb = (unsigned short*)(wsf + WS_XCATB);
    unsigned short* W_att1b = (unsigned short*)(wsf + WS_ATT1B);
    unsigned short* W_encb  = (unsigned short*)(wsf + WS_ENCB);
    unsigned short* W_w2b   = (unsigned short*)(wsf + WS_W2B);
    unsigned short* W_wdaT  = (unsigned short*)(wsf + WS_WDAT);
    unsigned short* W_weaT  = (unsigned short*)(wsf + WS_WEAT);
    unsigned short* W_woutT = (unsigned short*)(wsf + WS_WOUTT);
    unsigned short* W_wfbT  = (unsigned short*)(wsf + WS_WFBT);
    unsigned short* W_meanb = (unsigned short*)(wsf + WS_MEANB);
    unsigned short* W_wh0T  = (unsigned short*)(wsf + WS_WH0T);
    unsigned short* W_wc0T  = (unsigned short*)(wsf + WS_WC0T);
    unsigned short* W_hist  = (unsigned short*)(wsf + WS_HIST);

    k_sort<<<1, 64, 0, stream>>>(captions, clen, out, wsi);
    k_prep<<<256, 256, 0, stream>>>(feat, wsi, W_encb, W_mean, W_meanb);
    k_trbf<<<dim3(16, 64), 256, 0, stream>>>(Wh0, W_wh0T, 2048, 512);
    k_trbf<<<dim3(16, 64), 256, 0, stream>>>(Wc0, W_wc0T, 2048, 512);
    k_h0c0m<<<16, 256, 0, stream>>>(W_meanb, W_wh0T, W_wc0T, bh0, bc0,
                                    W_h, W_c, W_xcatb);
    k_w2b<<<dim3(12, 2048), 256, 0, stream>>>(Wih, Whh, W_w2b);
    k_trbf<<<dim3(16, 16), 256, 0, stream>>>(Wda, W_wdaT, 512, 512);
    k_trbf<<<dim3(16, 64), 256, 0, stream>>>(Wea, W_weaT, 2048, 512);
    k_trbf<<<dim3(938, 16), 256, 0, stream>>>(Wout, W_woutT, 512, 30000);
    k_trbf<<<dim3(64, 16), 256, 0, stream>>>(Wfb, W_wfbT, 512, 2048);
    k_att1<<<dim3(98, 2), 256, 0, stream>>>(W_encb, W_weaT, bea, W_att1b);

    for (int t = 0; t < NTD; t++) {
        k_step1<<<dim3(32, 4), 512, 0, stream>>>(emb, W_wdaT, bda, Wfa, bfa, wsi,
                                                 W_h, W_att1b, W_encb, W_wfbT, bfb,
                                                 W_xcatb, out, t);
        k_gateslstm<<<32, 512, 0, stream>>>(W_w2b, W_xcatb, bih, bhh, wsi,
                                            W_h, W_c, W_hist, t);
    }
    k_preds_all<<<dim3(118, 10), 256, 0, stream>>>(W_woutT, bout, W_hist, wsi, out);
}